// Round 11
// baseline (94.278 us; speedup 1.0000x reference)
//
#include <hip/hip_runtime.h>

// GraphCodeBertCPDP forward on MI355X (gfx950) — round 11.
// vs round 10: (a) znorm fused into mega tail (wsum-norm pattern proven in
// r8-r10; r5's failure was the stencil-coverage bug, not the norms) — one
// fewer launch; (b) softmax max/sum via wave-0 shuffle (5 barriers vs ~16);
// (c) hB XOR-swizzled + vectorized bf16x8 logit reads; (d) ortho_partial
// 256-thread (f-range split 2x). Launches: prep, mega, ortho_partial, ortho_final.
// Output layout (f32): [0:512) logits_cls | [512:66048) h_file |
//   [66048:98816) z_shared | [98816:131584) z_private | [131584:164352) att_w
//   [164352:164864) domain_logits | [164864] ortho

typedef __attribute__((ext_vector_type(8))) short bf16x8;
typedef __attribute__((ext_vector_type(4))) short bf16x4;
typedef __attribute__((ext_vector_type(4))) float f32x4;
typedef __attribute__((ext_vector_type(8))) float f32x8;

__device__ __forceinline__ unsigned short f2bf(float f) {
  union { float f; unsigned int i; } v; v.f = f;
  unsigned int r = v.i + 0x7FFFu + ((v.i >> 16) & 1u);
  return (unsigned short)(r >> 16);
}
__device__ __forceinline__ float bf2f(unsigned short u) {
  union { unsigned int i; float f; } v; v.i = ((unsigned int)u) << 16; return v.f;
}
__device__ __forceinline__ float cvt4dot(bf16x4 v, f32x4* o) {
  (*o)[0] = bf2f(((unsigned short*)&v)[0]); (*o)[1] = bf2f(((unsigned short*)&v)[1]);
  (*o)[2] = bf2f(((unsigned short*)&v)[2]); (*o)[3] = bf2f(((unsigned short*)&v)[3]);
  return 0.f;
}
__device__ __forceinline__ int degf(int p) {  // degree+1 (self-loop)
  return 5 - (p < 2 ? 2 - p : 0) - (p > 125 ? p - 125 : 0);
}
__device__ __forceinline__ float wsum(float v) {
#pragma unroll
  for (int o = 1; o < 64; o <<= 1) v += __shfl_xor(v, o);
  return v;
}

// ---- prep: cvt-transpose W1/W2 (tiled) + flat bf16 cvt of Ws/Wp/Wd1 ------
__global__ void prep_weights(const float* __restrict__ W1, const float* __restrict__ W2,
                             const float* __restrict__ Ws, const float* __restrict__ Wp,
                             const float* __restrict__ Wd1,
                             unsigned short* __restrict__ W1t, unsigned short* __restrict__ W2t,
                             unsigned short* __restrict__ WsbG, unsigned short* __restrict__ WpbG,
                             unsigned short* __restrict__ Wd1bG) {
  __shared__ float tile[32][33];
  int id = blockIdx.x;
  int tx = threadIdx.x, ty = threadIdx.y;  // 32 x 8
  if (id >= 256) {  // flat converts: 1024 f32 per block
    int id2 = id - 256;
    const float* src; unsigned short* dst; int blk;
    if (id2 < 32)      { src = Ws;  dst = WsbG;  blk = id2; }
    else if (id2 < 64) { src = Wp;  dst = WpbG;  blk = id2 - 32; }
    else               { src = Wd1; dst = Wd1bG; blk = id2 - 64; }
    int tid = ty * 32 + tx;
    int e0 = blk * 1024 + tid * 4;
    f32x4 v = *(const f32x4*)&src[e0];
    unsigned short o[4];
#pragma unroll
    for (int j = 0; j < 4; ++j) o[j] = f2bf(v[j]);
    *(bf16x4*)&dst[e0] = *(bf16x4*)o;
    return;
  }
  const float* src; unsigned short* dst; int R, C, bx, by;
  if (id < 192) { src = W1; dst = W1t; R = 768; C = 256; bx = (id % 8) * 32; by = (id / 8) * 32; }
  else { id -= 192; src = W2; dst = W2t; R = 256; C = 256; bx = (id % 8) * 32; by = (id / 8) * 32; }
#pragma unroll
  for (int j = 0; j < 32; j += 8)
    tile[ty + j][tx] = src[(by + ty + j) * C + bx + tx];
  __syncthreads();
#pragma unroll
  for (int j = 0; j < 32; j += 8)
    dst[(bx + ty + j) * R + by + tx] = f2bf(tile[tx][ty + j]);
}

// --------------------------- megakernel -----------------------------------
__global__ __launch_bounds__(1024) void mega(const float* __restrict__ A,
    const unsigned short* __restrict__ W1t, const float* __restrict__ b1,
    const unsigned short* __restrict__ W2t, const float* __restrict__ b2,
    const float* __restrict__ attn_w, const float* __restrict__ attn_b,
    const unsigned short* __restrict__ WsbG, const float* __restrict__ bs,
    const unsigned short* __restrict__ WpbG, const float* __restrict__ bp,
    const float* __restrict__ cls_w, const int* __restrict__ labels,
    const unsigned short* __restrict__ Wd1bG, const float* __restrict__ bd1,
    const float* __restrict__ Wd2, const float* __restrict__ bd2,
    float* __restrict__ zsn_g, float* __restrict__ zpn_g,
    float* __restrict__ out) {
  __shared__ __align__(16) char lds[131072];
  // phase1 staging
  unsigned short* sA1 = (unsigned short*)lds;            // [2][128][64] bf16, 32 KB
  unsigned short* sB1 = (unsigned short*)(lds + 32768);  // [2][256][64] bf16, 64 KB
  // post-phase1 overlays
  unsigned short* H1  = (unsigned short*)lds;            // [128][256] bf16 @ [0,64K)
  unsigned short* G1L = (unsigned short*)(lds + 65536);  // [128][256] bf16 swz @ [64K,128K)
  // phase2 overlays
  unsigned short* sB2 = (unsigned short*)lds;            // [2][256][64] bf16 @ [0,64K)
  unsigned short* H2  = (unsigned short*)lds;            // [128][256] bf16 @ [0,64K)
  unsigned short* hB  = (unsigned short*)(lds + 65536);  // [128][256] bf16 swz @ [64K,128K)
  // head-weight overlays
  unsigned short* Wlo = (unsigned short*)lds;            // 64 KB: Wsb then Wd1b
  unsigned short* Whi = (unsigned short*)(lds + 65536);  // 64 KB: Wpb
  __shared__ float awS[256];
  __shared__ float lgS[128];
  __shared__ float redM[4];
  __shared__ float scr[1024];
  __shared__ float hfS[256];
  __shared__ float zsS[128], zpS[128], znS[128];
  __shared__ float redS[16];

  const int t = threadIdx.x;
  const int wave = t >> 6, lane = t & 63;
  const int wr = wave >> 2, wc = wave & 3;              // 4x4 waves, 32x64 tiles
  const int file = blockIdx.x;
  const long rowA = (long)file * 128;

  if (t < 256) awS[t] = attn_w[t];

  f32x4 acc[2][4];
#pragma unroll
  for (int m = 0; m < 2; ++m)
#pragma unroll
    for (int n = 0; n < 4; ++n) acc[m][n] = (f32x4)0.0f;

  // ======================= phase 1: H1 = A @ W1t^T =========================
  const int arow = t >> 3, acol = (t & 7) * 8;
  const int aswz = arow * 64 + (acol ^ ((arow & 7) << 3));
  f32x8 areg;
#define ISSUE_A1(kt) areg = *(const f32x8*)&A[(rowA + arow) * 768 + (kt) * 64 + acol]
#define WRITE_A1(buf) { unsigned short u[8];                                      \
    _Pragma("unroll") for (int j = 0; j < 8; ++j) u[j] = f2bf(areg[j]);           \
    *(bf16x8*)&sA1[(buf) * 8192 + aswz] = *(bf16x8*)u; }
#define ISSUE_B1(kt, buf) _Pragma("unroll") for (int it = 0; it < 2; ++it) {      \
    int flat = (it * 1024 + t) * 8;                                               \
    int n = flat >> 6, k = flat & 63;                                             \
    const unsigned short* g = W1t + n * 768 + (kt) * 64 + (k ^ ((n & 7) << 3));   \
    __builtin_amdgcn_global_load_lds(                                             \
        (const __attribute__((address_space(1))) unsigned int*)g,                 \
        (__attribute__((address_space(3))) unsigned int*)                         \
            &sB1[(buf) * 16384 + (it * 16 + wave) * 512], 16, 0, 0); }

  ISSUE_A1(0); ISSUE_B1(0, 0); WRITE_A1(0);
  __syncthreads();
  for (int kt = 0; kt < 12; ++kt) {
    const int cur = kt & 1, nxt = cur ^ 1;
    if (kt + 1 < 12) { ISSUE_A1(kt + 1); ISSUE_B1(kt + 1, nxt); }
#pragma unroll
    for (int kk = 0; kk < 2; ++kk) {
      const int kb = kk * 32 + (lane >> 4) * 8;
      bf16x8 af[2], bfr[4];
#pragma unroll
      for (int m = 0; m < 2; ++m) {
        int r = wr * 32 + m * 16 + (lane & 15);
        af[m] = *(const bf16x8*)&sA1[cur * 8192 + r * 64 + (kb ^ ((r & 7) << 3))];
      }
#pragma unroll
      for (int n = 0; n < 4; ++n) {
        int r = wc * 64 + n * 16 + (lane & 15);
        bfr[n] = *(const bf16x8*)&sB1[cur * 16384 + r * 64 + (kb ^ ((r & 7) << 3))];
      }
#pragma unroll
      for (int m = 0; m < 2; ++m)
#pragma unroll
        for (int n = 0; n < 4; ++n)
          acc[m][n] = __builtin_amdgcn_mfma_f32_16x16x32_bf16(af[m], bfr[n], acc[m][n], 0, 0, 0);
    }
    if (kt + 1 < 12) WRITE_A1(nxt);
    __syncthreads();
  }
  // acc -> H1 (bf16).  C/D layout: col = lane&15, row = (lane>>4)*4+j
#pragma unroll
  for (int m = 0; m < 2; ++m)
#pragma unroll
    for (int n = 0; n < 4; ++n) {
      int r = wr * 32 + m * 16 + (lane >> 4) * 4;
      int c = wc * 64 + n * 16 + (lane & 15);
#pragma unroll
      for (int j = 0; j < 4; ++j) H1[(r + j) * 256 + c] = f2bf(acc[m][n][j]);
    }
  __syncthreads();
  // stencil1 + b1 + relu -> G1L (swizzled cols); it<8 covers ALL 128 lines
#pragma unroll
  for (int it = 0; it < 8; ++it) {
    int g = it * 1024 + t;
    int l = g >> 6, c0 = (g & 63) * 4;
    int dl = degf(l);
    f32x4 s = (f32x4)0.0f;
#pragma unroll
    for (int o = -2; o <= 2; ++o) {
      int q = l + o;
      if (q < 0 || q > 127) continue;
      float w = __frsqrt_rn((float)(dl * degf(q)));
      bf16x4 hv4 = *(const bf16x4*)&H1[q * 256 + c0];
      f32x4 hv; cvt4dot(hv4, &hv);
      s += w * hv;
    }
    f32x4 b = *(const f32x4*)&b1[c0];
    unsigned short o4[4];
#pragma unroll
    for (int j = 0; j < 4; ++j) o4[j] = f2bf(fmaxf(s[j] + b[j], 0.f));
    *(bf16x4*)&G1L[l * 256 + (c0 ^ ((l & 7) << 3))] = *(bf16x4*)o4;
  }
  __syncthreads();

  // ======================= phase 2: H2 = G1 @ W2t^T ========================
#pragma unroll
  for (int m = 0; m < 2; ++m)
#pragma unroll
    for (int n = 0; n < 4; ++n) acc[m][n] = (f32x4)0.0f;
#define ISSUE_B2(kt, buf) _Pragma("unroll") for (int it = 0; it < 2; ++it) {      \
    int flat = (it * 1024 + t) * 8;                                               \
    int n = flat >> 6, k = flat & 63;                                             \
    const unsigned short* g = W2t + n * 256 + (kt) * 64 + (k ^ ((n & 7) << 3));   \
    __builtin_amdgcn_global_load_lds(                                             \
        (const __attribute__((address_space(1))) unsigned int*)g,                 \
        (__attribute__((address_space(3))) unsigned int*)                         \
            &sB2[(buf) * 16384 + (it * 16 + wave) * 512], 16, 0, 0); }

  ISSUE_B2(0, 0);
  __syncthreads();
  for (int kt = 0; kt < 4; ++kt) {
    const int cur = kt & 1, nxt = cur ^ 1;
    if (kt + 1 < 4) ISSUE_B2(kt + 1, nxt);
#pragma unroll
    for (int kk = 0; kk < 2; ++kk) {
      const int kb = kk * 32 + (lane >> 4) * 8;
      bf16x8 af[2], bfr[4];
#pragma unroll
      for (int m = 0; m < 2; ++m) {
        int r = wr * 32 + m * 16 + (lane & 15);
        int col = kt * 64 + kb;
        af[m] = *(const bf16x8*)&G1L[r * 256 + (col ^ ((r & 7) << 3))];
      }
#pragma unroll
      for (int n = 0; n < 4; ++n) {
        int r = wc * 64 + n * 16 + (lane & 15);
        bfr[n] = *(const bf16x8*)&sB2[cur * 16384 + r * 64 + (kb ^ ((r & 7) << 3))];
      }
#pragma unroll
      for (int m = 0; m < 2; ++m)
#pragma unroll
        for (int n = 0; n < 4; ++n)
          acc[m][n] = __builtin_amdgcn_mfma_f32_16x16x32_bf16(af[m], bfr[n], acc[m][n], 0, 0, 0);
    }
    __syncthreads();
  }
  // acc -> H2 (bf16, over dead sB2)
#pragma unroll
  for (int m = 0; m < 2; ++m)
#pragma unroll
    for (int n = 0; n < 4; ++n) {
      int r = wr * 32 + m * 16 + (lane >> 4) * 4;
      int c = wc * 64 + n * 16 + (lane & 15);
#pragma unroll
      for (int j = 0; j < 4; ++j) H2[(r + j) * 256 + c] = f2bf(acc[m][n][j]);
    }
  __syncthreads();
  // stencil2 + b2 -> hB (SWIZZLED cols, over dead G1L); it<8 covers ALL lines
#pragma unroll
  for (int it = 0; it < 8; ++it) {
    int g = it * 1024 + t;
    int l = g >> 6, c0 = (g & 63) * 4;
    int dl = degf(l);
    f32x4 s = (f32x4)0.0f;
#pragma unroll
    for (int o = -2; o <= 2; ++o) {
      int q = l + o;
      if (q < 0 || q > 127) continue;
      float w = __frsqrt_rn((float)(dl * degf(q)));
      bf16x4 hv4 = *(const bf16x4*)&H2[q * 256 + c0];
      f32x4 hv; cvt4dot(hv4, &hv);
      s += w * hv;
    }
    f32x4 b = *(const f32x4*)&b2[c0];
    unsigned short o4[4];
#pragma unroll
    for (int j = 0; j < 4; ++j) o4[j] = f2bf(s[j] + b[j]);
    *(bf16x4*)&hB[l * 256 + (c0 ^ ((l & 7) << 3))] = *(bf16x4*)o4;
  }
  __syncthreads();
  // H2 region dead -> stage Wsb there.
#define ISSUE_WB(srcG, dstL, rounds) _Pragma("unroll") for (int it = 0; it < (rounds); ++it) { \
    const unsigned short* g = (srcG) + (it * 1024 + t) * 8;                        \
    __builtin_amdgcn_global_load_lds(                                              \
        (const __attribute__((address_space(1))) unsigned int*)g,                  \
        (__attribute__((address_space(3))) unsigned int*)                          \
            &(dstL)[(it * 16 + wave) * 512], 16, 0, 0); }
  ISSUE_WB(WsbG, Wlo, 4);

  // ======================= attention pooling (swizzled hB) =================
  {  // logits: 8 lanes/line, bf16x8 vector reads
    int l = t >> 3, p = t & 7;
    const int sw = (l & 7) << 3;
    float part = 0.f;
#pragma unroll
    for (int j = 0; j < 4; ++j) {
      int c0 = p * 32 + j * 8;
      bf16x8 hv = *(const bf16x8*)&hB[l * 256 + (c0 ^ sw)];
#pragma unroll
      for (int e = 0; e < 8; ++e) part += bf2f(((unsigned short*)&hv)[e]) * awS[c0 + e];
    }
    part += __shfl_xor(part, 1);
    part += __shfl_xor(part, 2);
    part += __shfl_xor(part, 4);
    if (p == 0) lgS[l] = part + attn_b[0];
  }
  __syncthreads();
  if (wave == 0) {  // max via wave-0 shuffle
    float m0 = fmaxf(lgS[lane], lgS[lane + 64]);
#pragma unroll
    for (int o = 1; o < 64; o <<= 1) m0 = fmaxf(m0, __shfl_xor(m0, o));
    if (lane == 0) redM[0] = m0;
  }
  __syncthreads();
  float mx = redM[0];
  if (t < 128) lgS[t] = expf(lgS[t] - mx);
  __syncthreads();
  if (wave == 0) {  // sum via wave-0 shuffle
    float s0 = wsum(lgS[lane] + lgS[lane + 64]);
    if (lane == 0) redM[1] = s0;
  }
  __syncthreads();
  float dn = redM[1];
  if (t < 128) {
    float w = lgS[t] / dn;
    lgS[t] = w;
    out[131584 + file * 128 + t] = w;
  }
  __syncthreads();
  {  // h_file partials (swizzled scalar reads, conflict-free per wave)
    int c = t & 255, grp = t >> 8;
    float s = 0.f;
    for (int l = grp * 32; l < grp * 32 + 32; ++l)
      s += lgS[l] * bf2f(hB[l * 256 + (c ^ ((l & 7) << 3))]);
    scr[grp * 256 + c] = s;
  }
  __syncthreads();
  if (t < 256) {
    float tot = scr[t] + scr[256 + t] + scr[512 + t] + scr[768 + t];
    hfS[t] = tot;
    out[512 + file * 256 + t] = tot;
  }
  __syncthreads();   // hB dead; Wsb landed

  // ======================= heads (LDS-staged bf16 weights) =================
  ISSUE_WB(WpbG, Whi, 4);   // stage Wpb into dead hB region during s-GEMV
  {  // s-GEMV
    int g = t >> 7, j = t & 127;
    float s = 0.f;
#pragma unroll 8
    for (int c = g * 32; c < g * 32 + 32; ++c) s += hfS[c] * bf2f(Wlo[c * 128 + j]);
    scr[g * 128 + j] = s;
  }
  __syncthreads();   // Wsb reads done; Wpb landed
  ISSUE_WB(Wd1bG, Wlo, 2);  // stage Wd1b over dead Wsb
  if (t < 128) {
    float zs = bs[t];
#pragma unroll
    for (int g = 0; g < 8; ++g) zs += scr[g * 128 + t];
    zsS[t] = zs;
    out[66048 + file * 128 + t] = zs;
    float s = wsum(zs * zs);
    if (lane == 0) redS[wave] = s;            // waves 0,1
  }
  __syncthreads();
  if (t == 0) redS[8] = fmaxf(sqrtf(redS[0] + redS[1]), 1e-12f);
  {  // p-GEMV
    int g = t >> 7, j = t & 127;
    float s = 0.f;
#pragma unroll 8
    for (int c = g * 32; c < g * 32 + 32; ++c) s += hfS[c] * bf2f(Whi[c * 128 + j]);
    scr[g * 128 + j] = s;
  }
  __syncthreads();
  if (t < 128) {
    float zsn = zsS[t] / redS[8];
    znS[t] = zsn;
    zsn_g[file * 128 + t] = zsn;
  } else if (t < 256) {
    int j = t - 128;
    float zp = bp[j];
#pragma unroll
    for (int g = 0; g < 8; ++g) zp += scr[g * 128 + j];
    zpS[j] = zp;
    out[98816 + file * 128 + j] = zp;
    float s = wsum(zp * zp);
    if (lane == 0) redS[wave] = s;            // waves 2,3
  }
  __syncthreads();
  if (t == 0) redS[9] = fmaxf(sqrtf(redS[2] + redS[3]), 1e-12f);
  __syncthreads();
  if (t < 128) zpn_g[file * 128 + t] = zpS[t] / redS[9];
  {  // AM-softmax: dot(zsn, cls_w[:,k]) and ||cls_w[:,k]||
    int j = t & 127;
    if (t >= 128 && t < 640) {
      int tt = t - 128;
      float v;
      if (tt < 128)       v = znS[j] * cls_w[j * 2 + 0];
      else if (tt < 256)  v = znS[j] * cls_w[j * 2 + 1];
      else if (tt < 384)  { float w0 = cls_w[j * 2 + 0]; v = w0 * w0; }
      else                { float w1 = cls_w[j * 2 + 1]; v = w1 * w1; }
      float s = wsum(v);
      if (lane == 0) redS[4 + (tt >> 7)] = s;  // redS[4..7]
    }
  }
  __syncthreads();
  if (t == 0) {
    float d0 = redS[4] + ((lane == 0) ? 0.f : 0.f), dd0, dd1;
    // each redS[4..7] already holds a full 128-sum (wsum over its wave covers
    // 64 lanes; the wave processed 128 j in 2 lanes? no: 128 threads = 2 waves)
    dd0 = 0.f; dd1 = 0.f;
    (void)d0;
  }
  __syncthreads();
  // NOTE: the 128-thread groups above span TWO waves each; redS[4+g] was
  // written by both waves of group g (same index!) — fix: use per-wave slots.
  // Redone correctly below with per-wave indexing.
  {
    int j = t & 127;
    if (t < 512) {
      float v;
      if (t < 128)       v = znS[j] * cls_w[j * 2 + 0];
      else if (t < 256)  v = znS[j] * cls_w[j * 2 + 1];
      else if (t < 384)  { float w0 = cls_w[j * 2 + 0]; v = w0 * w0; }
      else               { float w1 = cls_w[j * 2 + 1]; v = w1 * w1; }
      float s = wsum(v);
      if (lane == 0) redS[wave] = s;           // waves 0..7 (one slot each)
    }
  }
  __syncthreads();
  if (t == 0) {
    float d0 = redS[0] + redS[1], d1 = redS[2] + redS[3];
    float n0 = fmaxf(sqrtf(redS[4] + redS[5]), 1e-12f);
    float n1 = fmaxf(sqrtf(redS[6] + redS[7]), 1e-12f);
    int lab = labels[file];
    out[file * 2 + 0] = 30.0f * (d0 / n0 - 0.35f * (lab == 0 ? 1.f : 0.f));
    out[file * 2 + 1] = 30.0f * (d1 / n1 - 0.35f * (lab == 1 ? 1.f : 0.f));
  }
  __syncthreads();
  {  // domain GEMV: Wd1b from LDS
    int g = t >> 7, j = t & 127;
    float s = 0.f;
#pragma unroll 8
    for (int a = g * 16; a < g * 16 + 16; ++a) s += zsS[a] * bf2f(Wlo[a * 128 + j]);
    scr[g * 128 + j] = s;
  }
  __syncthreads();
  if (t < 128) {
    float dd = bd1[t];
#pragma unroll
    for (int g = 0; g < 8; ++g) dd += scr[g * 128 + t];
    dd = fmaxf(dd, 0.f);
    float s0 = wsum(dd * Wd2[t * 2 + 0]);
    if (lane == 0) redS[wave] = s0;           // waves 0,1
    float s1 = wsum(dd * Wd2[t * 2 + 1]);
    if (lane == 0) redS[4 + wave] = s1;
  }
  __syncthreads();
  if (t == 0) {
    out[164352 + file * 2 + 0] = redS[0] + redS[1] + bd2[0];
    out[164352 + file * 2 + 1] = redS[4] + redS[5] + bd2[1];
  }
#undef ISSUE_A1
#undef WRITE_A1
#undef ISSUE_B1
#undef ISSUE_B2
#undef ISSUE_WB
}

// ---------------- ortho: ||zsn^T @ zpn||_F --------------------------------
__global__ __launch_bounds__(256) void ortho_partial(const float* __restrict__ zsn,
                                                     const float* __restrict__ zpn,
                                                     float* __restrict__ partial) {
  const int a = blockIdx.x;
  const int b = threadIdx.x & 127, half = threadIdx.x >> 7;
  float s = 0.f;
  for (int f = half * 128; f < half * 128 + 128; ++f)
    s += zsn[f * 128 + a] * zpn[f * 128 + b];
  __shared__ float sc[256];
  sc[half * 128 + b] = s;
  __syncthreads();
  if (threadIdx.x < 128) {
    float v = sc[threadIdx.x] + sc[128 + threadIdx.x];
    sc[threadIdx.x] = v * v;
  }
  __syncthreads();
  for (int st = 64; st > 0; st >>= 1) {
    if (threadIdx.x < st) sc[threadIdx.x] += sc[threadIdx.x + st];
    __syncthreads();
  }
  if (threadIdx.x == 0) partial[a] = sc[0];
}

__global__ __launch_bounds__(128) void ortho_final(const float* __restrict__ partial,
                                                   float* __restrict__ out) {
  const int t = threadIdx.x;
  __shared__ float red[128];
  red[t] = partial[t]; __syncthreads();
  for (int st = 64; st > 0; st >>= 1) { if (t < st) red[t] += red[t + st]; __syncthreads(); }
  if (t == 0) out[164864] = sqrtf(red[0]);
}

extern "C" void kernel_launch(void* const* d_in, const int* in_sizes, int n_in,
                              void* d_out, int out_size, void* d_ws, size_t ws_size,
                              hipStream_t stream) {
  const float* line_emb = (const float*)d_in[0];
  const float* W1     = (const float*)d_in[1];
  const float* b1     = (const float*)d_in[2];
  const float* W2     = (const float*)d_in[3];
  const float* b2     = (const float*)d_in[4];
  const float* attn_w = (const float*)d_in[5];
  const float* attn_b = (const float*)d_in[6];
  const float* Ws     = (const float*)d_in[7];
  const float* bs     = (const float*)d_in[8];
  const float* Wp     = (const float*)d_in[9];
  const float* bp     = (const float*)d_in[10];
  const float* cls_w  = (const float*)d_in[11];
  const float* Wd1    = (const float*)d_in[12];
  const float* bd1    = (const float*)d_in[13];
  const float* Wd2    = (const float*)d_in[14];
  const float* bd2    = (const float*)d_in[15];
  const int* labels   = (const int*)d_in[18];

  char* ws = (char*)d_ws;
  unsigned short* W1t  = (unsigned short*)(ws + 0);        // [256][768] bf16
  unsigned short* W2t  = (unsigned short*)(ws + 393216);   // [256][256] bf16
  float* zsn           = (float*)(ws + 524288);            // [256][128] f32
  float* zpn           = (float*)(ws + 655360);            // [256][128] f32
  float* partial       = (float*)(ws + 786432);            // 128 f32
  unsigned short* WsbG = (unsigned short*)(ws + 1048576);  // [256][128] bf16
  unsigned short* WpbG = (unsigned short*)(ws + 1114112);  // [256][128] bf16
  unsigned short* Wd1bG= (unsigned short*)(ws + 1179648);  // [128][128] bf16
  float* out           = (float*)d_out;

  prep_weights<<<dim3(336), dim3(32, 8), 0, stream>>>(W1, W2, Ws, Wp, Wd1,
                                                      W1t, W2t, WsbG, WpbG, Wd1bG);
  mega<<<dim3(256), dim3(1024), 0, stream>>>(line_emb, W1t, b1, W2t, b2,
                                             attn_w, attn_b, WsbG, bs, WpbG, bp,
                                             cls_w, labels, Wd1bG, bd1, Wd2, bd2,
                                             zsn, zpn, out);
  ortho_partial<<<dim3(128), dim3(256), 0, stream>>>(zsn, zpn, partial);
  ortho_final<<<dim3(1), dim3(128), 0, stream>>>(partial, out);
}

// Round 13
// 70.196 us; speedup vs baseline: 1.3431x; 1.3431x over previous
//
#include <hip/hip_runtime.h>

// GraphCodeBertCPDP forward on MI355X (gfx950) — round 13 (= round 12 resubmit;
// round 12 died with infra UnresponsiveContainer before any bench data).
// = round 10 (best passing baseline, 73.2 us) + EXACTLY ONE change:
// znorm fused into mega's tail (zp norm via waves 2/3 -> redS[10..11] -> redS[9];
// zsn_g/zpn_g written from mega; znorm kernel removed). Nothing else differs
// from round 10 — r11 bundled 4 changes plus a dead duplicated block and
// regressed 73->94; this round isolates the fusion variable.
// Launches: prep_weights, mega, ortho_partial, ortho_final.
// Output layout (f32): [0:512) logits_cls | [512:66048) h_file |
//   [66048:98816) z_shared | [98816:131584) z_private | [131584:164352) att_w
//   [164352:164864) domain_logits | [164864] ortho

typedef __attribute__((ext_vector_type(8))) short bf16x8;
typedef __attribute__((ext_vector_type(4))) short bf16x4;
typedef __attribute__((ext_vector_type(4))) float f32x4;
typedef __attribute__((ext_vector_type(8))) float f32x8;

__device__ __forceinline__ unsigned short f2bf(float f) {
  union { float f; unsigned int i; } v; v.f = f;
  unsigned int r = v.i + 0x7FFFu + ((v.i >> 16) & 1u);
  return (unsigned short)(r >> 16);
}
__device__ __forceinline__ float bf2f(unsigned short u) {
  union { unsigned int i; float f; } v; v.i = ((unsigned int)u) << 16; return v.f;
}
__device__ __forceinline__ float cvt4dot(bf16x4 v, f32x4* o) {
  (*o)[0] = bf2f(((unsigned short*)&v)[0]); (*o)[1] = bf2f(((unsigned short*)&v)[1]);
  (*o)[2] = bf2f(((unsigned short*)&v)[2]); (*o)[3] = bf2f(((unsigned short*)&v)[3]);
  return 0.f;
}
__device__ __forceinline__ int degf(int p) {  // degree+1 (self-loop)
  return 5 - (p < 2 ? 2 - p : 0) - (p > 125 ? p - 125 : 0);
}
__device__ __forceinline__ float wsum(float v) {
#pragma unroll
  for (int o = 1; o < 64; o <<= 1) v += __shfl_xor(v, o);
  return v;
}

// ---- prep: cvt-transpose W1/W2 (tiled) + flat bf16 cvt of Ws/Wp/Wd1 ------
__global__ void prep_weights(const float* __restrict__ W1, const float* __restrict__ W2,
                             const float* __restrict__ Ws, const float* __restrict__ Wp,
                             const float* __restrict__ Wd1,
                             unsigned short* __restrict__ W1t, unsigned short* __restrict__ W2t,
                             unsigned short* __restrict__ WsbG, unsigned short* __restrict__ WpbG,
                             unsigned short* __restrict__ Wd1bG) {
  __shared__ float tile[32][33];
  int id = blockIdx.x;
  int tx = threadIdx.x, ty = threadIdx.y;  // 32 x 8
  if (id >= 256) {  // flat converts: 1024 f32 per block
    int id2 = id - 256;
    const float* src; unsigned short* dst; int blk;
    if (id2 < 32)      { src = Ws;  dst = WsbG;  blk = id2; }
    else if (id2 < 64) { src = Wp;  dst = WpbG;  blk = id2 - 32; }
    else               { src = Wd1; dst = Wd1bG; blk = id2 - 64; }
    int tid = ty * 32 + tx;
    int e0 = blk * 1024 + tid * 4;
    f32x4 v = *(const f32x4*)&src[e0];
    unsigned short o[4];
#pragma unroll
    for (int j = 0; j < 4; ++j) o[j] = f2bf(v[j]);
    *(bf16x4*)&dst[e0] = *(bf16x4*)o;
    return;
  }
  const float* src; unsigned short* dst; int R, C, bx, by;
  if (id < 192) { src = W1; dst = W1t; R = 768; C = 256; bx = (id % 8) * 32; by = (id / 8) * 32; }
  else { id -= 192; src = W2; dst = W2t; R = 256; C = 256; bx = (id % 8) * 32; by = (id / 8) * 32; }
#pragma unroll
  for (int j = 0; j < 32; j += 8)
    tile[ty + j][tx] = src[(by + ty + j) * C + bx + tx];
  __syncthreads();
#pragma unroll
  for (int j = 0; j < 32; j += 8)
    dst[(bx + ty + j) * R + by + tx] = f2bf(tile[tx][ty + j]);
}

// --------------------------- megakernel -----------------------------------
__global__ __launch_bounds__(1024) void mega(const float* __restrict__ A,
    const unsigned short* __restrict__ W1t, const float* __restrict__ b1,
    const unsigned short* __restrict__ W2t, const float* __restrict__ b2,
    const float* __restrict__ attn_w, const float* __restrict__ attn_b,
    const unsigned short* __restrict__ WsbG, const float* __restrict__ bs,
    const unsigned short* __restrict__ WpbG, const float* __restrict__ bp,
    const float* __restrict__ cls_w, const int* __restrict__ labels,
    const unsigned short* __restrict__ Wd1bG, const float* __restrict__ bd1,
    const float* __restrict__ Wd2, const float* __restrict__ bd2,
    float* __restrict__ zsn_g, float* __restrict__ zpn_g,
    float* __restrict__ out) {
  __shared__ __align__(16) char lds[131072];
  // phase1 staging (round-8 layout)
  unsigned short* sA1 = (unsigned short*)lds;            // [2][128][64] bf16, 32 KB
  unsigned short* sB1 = (unsigned short*)(lds + 32768);  // [2][256][64] bf16, 64 KB
  // post-phase1 overlays
  unsigned short* H1  = (unsigned short*)lds;            // [128][256] bf16 @ [0,64K)
  unsigned short* G1L = (unsigned short*)(lds + 65536);  // [128][256] bf16 swz @ [64K,128K)
  // phase2 overlays
  unsigned short* sB2 = (unsigned short*)lds;            // [2][256][64] bf16 @ [0,64K)
  unsigned short* H2  = (unsigned short*)lds;            // [128][256] bf16 @ [0,64K)
  unsigned short* hB  = (unsigned short*)(lds + 65536);  // [128][256] bf16 @ [64K,128K)
  // head-weight overlays (after H2/hB die)
  unsigned short* Wlo = (unsigned short*)lds;            // 64 KB @ [0,64K):  Wsb then Wd1b
  unsigned short* Whi = (unsigned short*)(lds + 65536);  // 64 KB @ [64K,128K): Wpb
  __shared__ float awS[256];
  __shared__ float lgS[128];
  __shared__ float redM[64];
  __shared__ float scr[1024];
  __shared__ float hfS[256];
  __shared__ float zsS[128], zpS[128], znS[128];
  __shared__ float redS[16];

  const int t = threadIdx.x;
  const int wave = t >> 6, lane = t & 63;
  const int wr = wave >> 2, wc = wave & 3;              // 4x4 waves, 32x64 tiles
  const int file = blockIdx.x;
  const long rowA = (long)file * 128;

  if (t < 256) awS[t] = attn_w[t];

  f32x4 acc[2][4];
#pragma unroll
  for (int m = 0; m < 2; ++m)
#pragma unroll
    for (int n = 0; n < 4; ++n) acc[m][n] = (f32x4)0.0f;

  // ======================= phase 1: H1 = A @ W1t^T (round-8 loop) =========
  const int arow = t >> 3, acol = (t & 7) * 8;
  const int aswz = arow * 64 + (acol ^ ((arow & 7) << 3));
  f32x8 areg;
#define ISSUE_A1(kt) areg = *(const f32x8*)&A[(rowA + arow) * 768 + (kt) * 64 + acol]
#define WRITE_A1(buf) { unsigned short u[8];                                      \
    _Pragma("unroll") for (int j = 0; j < 8; ++j) u[j] = f2bf(areg[j]);           \
    *(bf16x8*)&sA1[(buf) * 8192 + aswz] = *(bf16x8*)u; }
#define ISSUE_B1(kt, buf) _Pragma("unroll") for (int it = 0; it < 2; ++it) {      \
    int flat = (it * 1024 + t) * 8;                                               \
    int n = flat >> 6, k = flat & 63;                                             \
    const unsigned short* g = W1t + n * 768 + (kt) * 64 + (k ^ ((n & 7) << 3));   \
    __builtin_amdgcn_global_load_lds(                                             \
        (const __attribute__((address_space(1))) unsigned int*)g,                 \
        (__attribute__((address_space(3))) unsigned int*)                         \
            &sB1[(buf) * 16384 + (it * 16 + wave) * 512], 16, 0, 0); }

  ISSUE_A1(0); ISSUE_B1(0, 0); WRITE_A1(0);
  __syncthreads();
  for (int kt = 0; kt < 12; ++kt) {
    const int cur = kt & 1, nxt = cur ^ 1;
    if (kt + 1 < 12) { ISSUE_A1(kt + 1); ISSUE_B1(kt + 1, nxt); }
#pragma unroll
    for (int kk = 0; kk < 2; ++kk) {
      const int kb = kk * 32 + (lane >> 4) * 8;
      bf16x8 af[2], bfr[4];
#pragma unroll
      for (int m = 0; m < 2; ++m) {
        int r = wr * 32 + m * 16 + (lane & 15);
        af[m] = *(const bf16x8*)&sA1[cur * 8192 + r * 64 + (kb ^ ((r & 7) << 3))];
      }
#pragma unroll
      for (int n = 0; n < 4; ++n) {
        int r = wc * 64 + n * 16 + (lane & 15);
        bfr[n] = *(const bf16x8*)&sB1[cur * 16384 + r * 64 + (kb ^ ((r & 7) << 3))];
      }
#pragma unroll
      for (int m = 0; m < 2; ++m)
#pragma unroll
        for (int n = 0; n < 4; ++n)
          acc[m][n] = __builtin_amdgcn_mfma_f32_16x16x32_bf16(af[m], bfr[n], acc[m][n], 0, 0, 0);
    }
    if (kt + 1 < 12) WRITE_A1(nxt);
    __syncthreads();
  }
  // acc -> H1 (bf16).  C/D layout: col = lane&15, row = (lane>>4)*4+j
#pragma unroll
  for (int m = 0; m < 2; ++m)
#pragma unroll
    for (int n = 0; n < 4; ++n) {
      int r = wr * 32 + m * 16 + (lane >> 4) * 4;
      int c = wc * 64 + n * 16 + (lane & 15);
#pragma unroll
      for (int j = 0; j < 4; ++j) H1[(r + j) * 256 + c] = f2bf(acc[m][n][j]);
    }
  __syncthreads();
  // stencil1 + b1 + relu -> G1L (swizzled cols); it<8 covers ALL 128 lines
#pragma unroll
  for (int it = 0; it < 8; ++it) {
    int g = it * 1024 + t;
    int l = g >> 6, c0 = (g & 63) * 4;
    int dl = degf(l);
    f32x4 s = (f32x4)0.0f;
#pragma unroll
    for (int o = -2; o <= 2; ++o) {
      int q = l + o;
      if (q < 0 || q > 127) continue;
      float w = __frsqrt_rn((float)(dl * degf(q)));
      bf16x4 hv4 = *(const bf16x4*)&H1[q * 256 + c0];
      f32x4 hv; cvt4dot(hv4, &hv);
      s += w * hv;
    }
    f32x4 b = *(const f32x4*)&b1[c0];
    unsigned short o4[4];
#pragma unroll
    for (int j = 0; j < 4; ++j) o4[j] = f2bf(fmaxf(s[j] + b[j], 0.f));
    *(bf16x4*)&G1L[l * 256 + (c0 ^ ((l & 7) << 3))] = *(bf16x4*)o4;
  }
  __syncthreads();

  // ======================= phase 2: H2 = G1 @ W2t^T ========================
#pragma unroll
  for (int m = 0; m < 2; ++m)
#pragma unroll
    for (int n = 0; n < 4; ++n) acc[m][n] = (f32x4)0.0f;
#define ISSUE_B2(kt, buf) _Pragma("unroll") for (int it = 0; it < 2; ++it) {      \
    int flat = (it * 1024 + t) * 8;                                               \
    int n = flat >> 6, k = flat & 63;                                             \
    const unsigned short* g = W2t + n * 256 + (kt) * 64 + (k ^ ((n & 7) << 3));   \
    __builtin_amdgcn_global_load_lds(                                             \
        (const __attribute__((address_space(1))) unsigned int*)g,                 \
        (__attribute__((address_space(3))) unsigned int*)                         \
            &sB2[(buf) * 16384 + (it * 16 + wave) * 512], 16, 0, 0); }

  ISSUE_B2(0, 0);
  __syncthreads();
  for (int kt = 0; kt < 4; ++kt) {
    const int cur = kt & 1, nxt = cur ^ 1;
    if (kt + 1 < 4) ISSUE_B2(kt + 1, nxt);
#pragma unroll
    for (int kk = 0; kk < 2; ++kk) {
      const int kb = kk * 32 + (lane >> 4) * 8;
      bf16x8 af[2], bfr[4];
#pragma unroll
      for (int m = 0; m < 2; ++m) {
        int r = wr * 32 + m * 16 + (lane & 15);
        int col = kt * 64 + kb;
        af[m] = *(const bf16x8*)&G1L[r * 256 + (col ^ ((r & 7) << 3))];
      }
#pragma unroll
      for (int n = 0; n < 4; ++n) {
        int r = wc * 64 + n * 16 + (lane & 15);
        bfr[n] = *(const bf16x8*)&sB2[cur * 16384 + r * 64 + (kb ^ ((r & 7) << 3))];
      }
#pragma unroll
      for (int m = 0; m < 2; ++m)
#pragma unroll
        for (int n = 0; n < 4; ++n)
          acc[m][n] = __builtin_amdgcn_mfma_f32_16x16x32_bf16(af[m], bfr[n], acc[m][n], 0, 0, 0);
    }
    __syncthreads();
  }
  // acc -> H2 (bf16, over dead sB2)
#pragma unroll
  for (int m = 0; m < 2; ++m)
#pragma unroll
    for (int n = 0; n < 4; ++n) {
      int r = wr * 32 + m * 16 + (lane >> 4) * 4;
      int c = wc * 64 + n * 16 + (lane & 15);
#pragma unroll
      for (int j = 0; j < 4; ++j) H2[(r + j) * 256 + c] = f2bf(acc[m][n][j]);
    }
  __syncthreads();
  // stencil2 + b2 -> hB (over dead G1L); it<8 covers ALL 128 lines
#pragma unroll
  for (int it = 0; it < 8; ++it) {
    int g = it * 1024 + t;
    int l = g >> 6, c0 = (g & 63) * 4;
    int dl = degf(l);
    f32x4 s = (f32x4)0.0f;
#pragma unroll
    for (int o = -2; o <= 2; ++o) {
      int q = l + o;
      if (q < 0 || q > 127) continue;
      float w = __frsqrt_rn((float)(dl * degf(q)));
      bf16x4 hv4 = *(const bf16x4*)&H2[q * 256 + c0];
      f32x4 hv; cvt4dot(hv4, &hv);
      s += w * hv;
    }
    f32x4 b = *(const f32x4*)&b2[c0];
    unsigned short o4[4];
#pragma unroll
    for (int j = 0; j < 4; ++j) o4[j] = f2bf(s[j] + b[j]);
    *(bf16x4*)&hB[l * 256 + c0] = *(bf16x4*)o4;
  }
  __syncthreads();
  // H2 region [0,64K) now dead -> stage Wsb (bf16 [256][128], 64 KB) there.
#define ISSUE_WB(srcG, dstL, rounds) _Pragma("unroll") for (int it = 0; it < (rounds); ++it) { \
    const unsigned short* g = (srcG) + (it * 1024 + t) * 8;                        \
    __builtin_amdgcn_global_load_lds(                                              \
        (const __attribute__((address_space(1))) unsigned int*)g,                  \
        (__attribute__((address_space(3))) unsigned int*)                          \
            &(dstL)[(it * 16 + wave) * 512], 16, 0, 0); }
  ISSUE_WB(WsbG, Wlo, 4);

  // ======================= attention pooling (reads hB) ====================
  {  // logits: 8 lanes per line, rotated channel order
    int l = t >> 3, p = t & 7;
    float part = 0.f;
#pragma unroll 4
    for (int j = 0; j < 32; ++j) {
      int c = p * 32 + ((j + 4 * p + l) & 31);
      part += bf2f(hB[l * 256 + c]) * awS[c];
    }
    part += __shfl_xor(part, 1);
    part += __shfl_xor(part, 2);
    part += __shfl_xor(part, 4);
    if (p == 0) lgS[l] = part + attn_b[0];
  }
  __syncthreads();
  if (t < 64) redM[t] = fmaxf(lgS[t], lgS[t + 64]);
  __syncthreads();
  for (int s = 32; s > 0; s >>= 1) {
    if (t < s) redM[t] = fmaxf(redM[t], redM[t + s]);
    __syncthreads();
  }
  float mx = redM[0];
  __syncthreads();
  if (t < 128) lgS[t] = expf(lgS[t] - mx);
  __syncthreads();
  if (t < 64) redM[t] = lgS[t] + lgS[t + 64];
  __syncthreads();
  for (int s = 32; s > 0; s >>= 1) {
    if (t < s) redM[t] += redM[t + s];
    __syncthreads();
  }
  float dn = redM[0];
  __syncthreads();
  if (t < 128) {
    float w = lgS[t] / dn;
    lgS[t] = w;
    out[131584 + file * 128 + t] = w;
  }
  __syncthreads();
  {  // h_file partials
    int c = t & 255, grp = t >> 8;
    float s = 0.f;
    for (int l = grp * 32; l < grp * 32 + 32; ++l) s += lgS[l] * bf2f(hB[l * 256 + c]);
    scr[grp * 256 + c] = s;
  }
  __syncthreads();
  if (t < 256) {
    float tot = scr[t] + scr[256 + t] + scr[512 + t] + scr[768 + t];
    hfS[t] = tot;
    out[512 + file * 256 + t] = tot;
  }
  __syncthreads();   // hB dead from here; Wsb landed (barrier drains vmcnt)

  // ======================= heads (LDS-staged bf16 weights) =================
  ISSUE_WB(WpbG, Whi, 4);   // stage Wpb into dead hB region during s-GEMV
  {  // s-GEMV: 8 c-groups x 128 j, 32-deep, Wsb from LDS
    int g = t >> 7, j = t & 127;
    float s = 0.f;
#pragma unroll 8
    for (int c = g * 32; c < g * 32 + 32; ++c) s += hfS[c] * bf2f(Wlo[c * 128 + j]);
    scr[g * 128 + j] = s;
  }
  __syncthreads();   // Wsb reads done; Wpb landed
  ISSUE_WB(Wd1bG, Wlo, 2);  // stage Wd1b over dead Wsb during z_s combine
  if (t < 128) {
    float zs = bs[t];
#pragma unroll
    for (int g = 0; g < 8; ++g) zs += scr[g * 128 + t];
    zsS[t] = zs;
    out[66048 + file * 128 + t] = zs;
    float s = wsum(zs * zs);
    if (lane == 0) redS[wave] = s;            // waves 0,1
  }
  __syncthreads();
  if (t == 0) redS[8] = fmaxf(sqrtf(redS[0] + redS[1]), 1e-12f);
  {  // p-GEMV: Wpb from LDS
    int g = t >> 7, j = t & 127;
    float s = 0.f;
#pragma unroll 8
    for (int c = g * 32; c < g * 32 + 32; ++c) s += hfS[c] * bf2f(Whi[c * 128 + j]);
    scr[g * 128 + j] = s;
  }
  __syncthreads();
  if (t < 128) {
    float zsn = zsS[t] / redS[8];
    znS[t] = zsn;
    zsn_g[file * 128 + t] = zsn;             // fused znorm: zsn out
  } else if (t < 256) {
    int j = t - 128;
    float zp = bp[j];
#pragma unroll
    for (int g = 0; g < 8; ++g) zp += scr[g * 128 + j];
    zpS[j] = zp;
    out[98816 + file * 128 + j] = zp;
    float s = wsum(zp * zp);
    if (lane == 0) redS[10 + (wave - 2)] = s;  // waves 2,3 -> redS[10],redS[11]
  }
  __syncthreads();
  if (t == 0) redS[9] = fmaxf(sqrtf(redS[10] + redS[11]), 1e-12f);
  __syncthreads();
  if (t < 128) zpn_g[file * 128 + t] = zpS[t] / redS[9];  // fused znorm: zpn out
  {  // AM-softmax: dot(zsn, cls_w[:,k]) and ||cls_w[:,k]||
    int j = t & 127;
    if (t < 512) {
      float v;
      if (t < 128)       v = znS[j] * cls_w[j * 2 + 0];
      else if (t < 256)  v = znS[j] * cls_w[j * 2 + 1];
      else if (t < 384)  { float w0 = cls_w[j * 2 + 0]; v = w0 * w0; }
      else               { float w1 = cls_w[j * 2 + 1]; v = w1 * w1; }
      float s = wsum(v);
      if (lane == 0) redS[wave] = s;           // waves 0..7
    }
  }
  __syncthreads();
  if (t == 0) {
    float d0 = redS[0] + redS[1], d1 = redS[2] + redS[3];
    float n0 = fmaxf(sqrtf(redS[4] + redS[5]), 1e-12f);
    float n1 = fmaxf(sqrtf(redS[6] + redS[7]), 1e-12f);
    int lab = labels[file];
    out[file * 2 + 0] = 30.0f * (d0 / n0 - 0.35f * (lab == 0 ? 1.f : 0.f));
    out[file * 2 + 1] = 30.0f * (d1 / n1 - 0.35f * (lab == 1 ? 1.f : 0.f));
  }
  __syncthreads();
  {  // domain GEMV: Wd1b [128][128] bf16 from LDS, 8 groups x 16-deep
    int g = t >> 7, j = t & 127;
    float s = 0.f;
#pragma unroll 8
    for (int a = g * 16; a < g * 16 + 16; ++a) s += zsS[a] * bf2f(Wlo[a * 128 + j]);
    scr[g * 128 + j] = s;
  }
  __syncthreads();
  if (t < 128) {
    float dd = bd1[t];
#pragma unroll
    for (int g = 0; g < 8; ++g) dd += scr[g * 128 + t];
    dd = fmaxf(dd, 0.f);
    float s0 = wsum(dd * Wd2[t * 2 + 0]);
    if (lane == 0) redS[wave] = s0;           // waves 0,1
    float s1 = wsum(dd * Wd2[t * 2 + 1]);
    if (lane == 0) redS[4 + wave] = s1;
  }
  __syncthreads();
  if (t == 0) {
    out[164352 + file * 2 + 0] = redS[0] + redS[1] + bd2[0];
    out[164352 + file * 2 + 1] = redS[4] + redS[5] + bd2[1];
  }
#undef ISSUE_A1
#undef WRITE_A1
#undef ISSUE_B1
#undef ISSUE_B2
#undef ISSUE_WB
}

// ---------------- ortho: ||zsn^T @ zpn||_F --------------------------------
__global__ __launch_bounds__(128) void ortho_partial(const float* __restrict__ zsn,
                                                     const float* __restrict__ zpn,
                                                     float* __restrict__ partial) {
  const int a = blockIdx.x, b = threadIdx.x;
  float s = 0.f;
  for (int f = 0; f < 256; ++f) s += zsn[f * 128 + a] * zpn[f * 128 + b];
  __shared__ float red[128];
  red[b] = s * s; __syncthreads();
  for (int st = 64; st > 0; st >>= 1) { if (b < st) red[b] += red[b + st]; __syncthreads(); }
  if (b == 0) partial[a] = red[0];
}

__global__ __launch_bounds__(128) void ortho_final(const float* __restrict__ partial,
                                                   float* __restrict__ out) {
  const int t = threadIdx.x;
  __shared__ float red[128];
  red[t] = partial[t]; __syncthreads();
  for (int st = 64; st > 0; st >>= 1) { if (t < st) red[t] += red[t + st]; __syncthreads(); }
  if (t == 0) out[164864] = sqrtf(red[0]);
}

extern "C" void kernel_launch(void* const* d_in, const int* in_sizes, int n_in,
                              void* d_out, int out_size, void* d_ws, size_t ws_size,
                              hipStream_t stream) {
  const float* line_emb = (const float*)d_in[0];
  const float* W1     = (const float*)d_in[1];
  const float* b1     = (const float*)d_in[2];
  const float* W2     = (const float*)d_in[3];
  const float* b2     = (const float*)d_in[4];
  const float* attn_w = (const float*)d_in[5];
  const float* attn_b = (const float*)d_in[6];
  const float* Ws     = (const float*)d_in[7];
  const float* bs     = (const float*)d_in[8];
  const float* Wp     = (const float*)d_in[9];
  const float* bp     = (const float*)d_in[10];
  const float* cls_w  = (const float*)d_in[11];
  const float* Wd1    = (const float*)d_in[12];
  const float* bd1    = (const float*)d_in[13];
  const float* Wd2    = (const float*)d_in[14];
  const float* bd2    = (const float*)d_in[15];
  const int* labels   = (const int*)d_in[18];

  char* ws = (char*)d_ws;
  unsigned short* W1t  = (unsigned short*)(ws + 0);        // [256][768] bf16
  unsigned short* W2t  = (unsigned short*)(ws + 393216);   // [256][256] bf16
  float* zsn           = (float*)(ws + 524288);            // [256][128] f32
  float* zpn           = (float*)(ws + 655360);            // [256][128] f32
  float* partial       = (float*)(ws + 786432);            // 128 f32
  unsigned short* WsbG = (unsigned short*)(ws + 1048576);  // [256][128] bf16
  unsigned short* WpbG = (unsigned short*)(ws + 1114112);  // [256][128] bf16
  unsigned short* Wd1bG= (unsigned short*)(ws + 1179648);  // [128][128] bf16
  float* out           = (float*)d_out;

  prep_weights<<<dim3(336), dim3(32, 8), 0, stream>>>(W1, W2, Ws, Wp, Wd1,
                                                      W1t, W2t, WsbG, WpbG, Wd1bG);
  mega<<<dim3(256), dim3(1024), 0, stream>>>(line_emb, W1t, b1, W2t, b2,
                                             attn_w, attn_b, WsbG, bs, WpbG, bp,
                                             cls_w, labels, Wd1bG, bd1, Wd2, bd2,
                                             zsn, zpn, out);
  ortho_partial<<<dim3(128), dim3(128), 0, stream>>>(zsn, zpn, partial);
  ortho_final<<<dim3(1), dim3(128), 0, stream>>>(partial, out);
}